// Round 12
// baseline (9471.895 us; speedup 1.0000x reference)
//
#include <hip/hip_runtime.h>
#include <hip/hip_bf16.h>

typedef __bf16 bf16;
typedef __bf16 bf16x8 __attribute__((ext_vector_type(8)));
typedef float  f32x4  __attribute__((ext_vector_type(4)));

#define SLICE   49152              // one 24-row x 2KB weight slice
#define ZOFF    (3 * SLICE)        // 2KB zero rows (pad tile for n-gate MFMA)
#define LDS_TOT (3 * SLICE + 2048) // 149504 B -> 1 block/CU

// ---------------------------------------------------------------------------
__global__ __launch_bounds__(256) void cast_f32_bf16(const float* __restrict__ in,
                                                     bf16* __restrict__ out) {
    size_t i = ((size_t)blockIdx.x * blockDim.x + threadIdx.x) * 8;
    float4 a = *(const float4*)(in + i);
    float4 b = *(const float4*)(in + i + 4);
    bf16x8 o;
    o[0] = (bf16)a.x; o[1] = (bf16)a.y; o[2] = (bf16)a.z; o[3] = (bf16)a.w;
    o[4] = (bf16)b.x; o[5] = (bf16)b.y; o[6] = (bf16)b.z; o[7] = (bf16)b.w;
    *(bf16x8*)(out + i) = o;
}

// ---------------------------------------------------------------------------
__global__ __launch_bounds__(256) void transpose_cast(const float* __restrict__ in,
                                                      bf16* __restrict__ out,
                                                      int R, int C) {
    __shared__ float tile[32][33];
    int c0 = blockIdx.x * 32, r0 = blockIdx.y * 32;
    int tx = threadIdx.x & 31, ty = threadIdx.x >> 5;
    #pragma unroll
    for (int i = 0; i < 32; i += 8)
        tile[ty + i][tx] = in[(size_t)(r0 + ty + i) * C + c0 + tx];
    __syncthreads();
    #pragma unroll
    for (int i = 0; i < 32; i += 8)
        out[(size_t)(c0 + ty + i) * R + r0 + tx] = (bf16)tile[tx][ty + i];
}

// ---------------------------------------------------------------------------
template<bool BF16_OUT, bool HAS_BIAS>
__global__ __launch_bounds__(256) void gemm128(const bf16* __restrict__ A,
                                               const bf16* __restrict__ Bt,
                                               const float* __restrict__ bias,
                                               void* __restrict__ Cout,
                                               int M, int N, int K) {
    __shared__ bf16 sA[128][72];
    __shared__ bf16 sB[128][72];
    const int tid = threadIdx.x, lane = tid & 63, w = tid >> 6;
    const int wr = w >> 1, wc = w & 1;
    const int m0 = blockIdx.y * 128, n0 = blockIdx.x * 128;
    const int ml = lane & 15, kb = (lane >> 4) * 8;

    f32x4 acc[4][4] = {};
    const bf16* Ab = A  + (size_t)m0 * K;
    const bf16* Bb = Bt + (size_t)n0 * K;

    for (int kc = 0; kc < K; kc += 64) {
        #pragma unroll
        for (int i = 0; i < 4; ++i) {
            int c = tid + 256 * i;
            int row = c >> 3, col = (c & 7) * 8;
            *(uint4*)&sA[row][col] = *(const uint4*)(Ab + (size_t)row * K + kc + col);
            *(uint4*)&sB[row][col] = *(const uint4*)(Bb + (size_t)row * K + kc + col);
        }
        __syncthreads();
        #pragma unroll
        for (int ks = 0; ks < 2; ++ks) {
            bf16x8 af[4], bfr[4];
            #pragma unroll
            for (int i = 0; i < 4; ++i)
                af[i] = *(const bf16x8*)&sA[wr * 64 + i * 16 + ml][ks * 32 + kb];
            #pragma unroll
            for (int i = 0; i < 4; ++i)
                bfr[i] = *(const bf16x8*)&sB[wc * 64 + i * 16 + ml][ks * 32 + kb];
            #pragma unroll
            for (int mi = 0; mi < 4; ++mi)
                #pragma unroll
                for (int ni = 0; ni < 4; ++ni)
                    acc[mi][ni] = __builtin_amdgcn_mfma_f32_16x16x32_bf16(
                        af[mi], bfr[ni], acc[mi][ni], 0, 0, 0);
        }
        __syncthreads();
    }
    const int rbase = (lane >> 4) * 4;
    #pragma unroll
    for (int mi = 0; mi < 4; ++mi) {
        #pragma unroll
        for (int ni = 0; ni < 4; ++ni) {
            int col = n0 + wc * 64 + ni * 16 + ml;
            float bv = HAS_BIAS ? bias[col] : 0.f;
            #pragma unroll
            for (int r = 0; r < 4; ++r) {
                int row = m0 + wr * 64 + mi * 16 + rbase + r;
                float v = acc[mi][ni][r] + bv;
                if constexpr (BF16_OUT)
                    ((bf16*)Cout)[(size_t)row * N + col] = (bf16)v;
                else
                    ((float*)Cout)[(size_t)row * N + col] = v;
            }
        }
    }
}

// ---------------------------------------------------------------------------
// One K=1024 pass: A = 16 h-rows (cached global, r7-proven issue->drain->MFMA)
// against one 24-row LDS weight slice. Outputs: t1 = [r|z] tile, t2 = [n|pad].
// NOTE: rowp MUST include the per-lane K offset kb16 = (lane>>4)*16 bytes —
// dropping it was the r10/r11 wrong-answer bug (all lane groups fed K 0..7).
__device__ __forceinline__ void mm(const char* lds, int mat, const bf16* hsrc,
                                   int myrow, int ml, int kb16,
                                   f32x4& t1, f32x4& t2) {
    const char* rowp = (const char*)(hsrc + (size_t)myrow * 1024) + kb16;
    uint4 q[32];
    #pragma unroll
    for (int ks = 0; ks < 32; ++ks)
        asm volatile("global_load_dwordx4 %0, %1, off"
                     : "=v"(q[ks]) : "v"(rowp + ks * 64) : "memory");
    asm volatile("s_waitcnt vmcnt(0)" ::: "memory");
    __builtin_amdgcn_sched_barrier(0);

    const char* base = lds + mat * SLICE;
    const char* r1 = base + ml * 2048;
    const char* r2 = (ml < 8) ? (base + (16 + ml) * 2048) : (lds + ZOFF);
    const int sw = (ml & 7) << 4;
    #pragma unroll
    for (int ks = 0; ks < 32; ++ks) {
        bf16x8 af = __builtin_bit_cast(bf16x8, q[ks]);
        int ko = ks * 64 + kb16;
        bf16x8 bw1 = *(const bf16x8*)(r1 + (ko ^ sw));
        bf16x8 bw2 = *(const bf16x8*)(r2 + (ko ^ sw));
        t1 = __builtin_amdgcn_mfma_f32_16x16x32_bf16(af, bw1, t1, 0, 0, 0);
        t2 = __builtin_amdgcn_mfma_f32_16x16x32_bf16(af, bw2, t2, 0, 0, 0);
    }
}

// gates + state update + packed sc store (lanes ml<8 own col c0+ml, 4 rows)
__device__ __forceinline__ void do_gates(const float gr[4], const float gz[4],
                                         const float gn[4], f32x4 ht1, f32x4 ht2,
                                         float4 pv, float hreg[4],
                                         bf16* dst, int bq, int c0, int ml) {
    unsigned short hpk[4];
    #pragma unroll
    for (int r = 0; r < 4; ++r) {
        float ghr = ht1[r];
        float ghz = __shfl_xor(ht1[r], 8, 64);
        float ghn = ht2[r];
        float rr = 1.f / (1.f + __expf(-(gr[r] + ghr)));
        float zz = 1.f / (1.f + __expf(-(gz[r] + ghz)));
        float nn = tanhf(gn[r] + rr * ghn);
        float hold = hreg[r];
        float hn = (1.f - zz) * nn + zz * hold;
        float p = (r == 0) ? pv.x : (r == 1) ? pv.y : (r == 2) ? pv.z : pv.w;
        hn = p * hold + (1.f - p) * hn;
        hreg[r] = hn;
        hpk[r] = __builtin_bit_cast(unsigned short, (bf16)hn);
    }
    #pragma unroll
    for (int r = 0; r < 4; ++r) {
        unsigned nb = (unsigned)__shfl_xor((int)(unsigned)hpk[r], 1, 64);
        if ((ml & 1) == 0 && ml < 8) {
            unsigned pk = (unsigned)hpk[r] | (nb << 16);
            __hip_atomic_store((unsigned*)(dst + (size_t)(bq + r) * 1024 + c0 + ml), pk,
                               __ATOMIC_RELAXED, __HIP_MEMORY_SCOPE_AGENT);
        }
    }
}

// ---------------------------------------------------------------------------
// Merged 2-layer GRU scan, lag-2 schedule, ONE kernel, 128 blocks x 256 thr.
// Block owns 8 h-cols of BOTH layers. Beat s:
//   pre-poll : gx2 tiles = h1[s-2]@W2f  (h1[s-2] proven stable by beat-(s-1)
//              poll -> legal to read BEFORE this beat's poll; hides 1 RTT)
//   poll     : all 128 block flags >= s
//   phase B  : gh2 = h2[s-3]@Whh2; h2[s-2] gates+store
//   phase A  : gh1 = h1[s-1]@Whh1; h1[s] gates+store
// One monotone flag per block, unconditional publish -> deadlock-free,
// no placement assumptions. h reads cached (fresh addresses), stores sc.
__global__ __launch_bounds__(256, 1) void gru_merged(
    const bf16* __restrict__ WH1T, const bf16* __restrict__ W2fT,
    const bf16* __restrict__ WH2T, const bf16* __restrict__ gx1,
    const float* __restrict__ pad, const float* __restrict__ b2,
    bf16* __restrict__ h1buf,   // [512][64][1024]
    bf16* __restrict__ hs2,     // [512][64][1024]
    unsigned* __restrict__ fb) { // [128]
    extern __shared__ __align__(16) char lds[];
    const int tid = threadIdx.x, lane = tid & 63, wv = tid >> 6;
    const int ml = lane & 15;
    const int kb16 = (lane >> 4) * 16;
    const int c0 = blockIdx.x * 8;
    const int myrow = wv * 16 + ml;
    const int bq = wv * 16 + (lane >> 4) * 4;

    // ---- stage the three 24-row weight slices (swizzled) + zero rows
    const bf16* Wm[3] = {WH1T, W2fT, WH2T};
    #pragma unroll 1
    for (int i = 0; i < 36; ++i) {
        int c = tid + 256 * i;                 // 9216 chunks of 16B
        int row = c >> 7;                      // 0..71
        int koff = (c & 127) * 16;
        int mat = (row >= 48) ? 2 : (row >= 24 ? 1 : 0);
        int sr = row - mat * 24;
        int gate = sr >> 3, cx = sr & 7;
        const char* src = (const char*)Wm[mat] +
            ((size_t)(gate * 1024 + c0 + cx) * 1024) * 2 + koff;
        *(uint4*)(lds + mat * SLICE + sr * 2048 + (koff ^ ((sr & 7) << 4))) =
            *(const uint4*)src;
    }
    if (tid < 128) { uint4 z = {0, 0, 0, 0}; *(uint4*)(lds + ZOFF + tid * 16) = z; }
    __syncthreads();

    float b2r, b2z, b2n;
    {
        int c = c0 + (ml & 7);
        b2r = b2[c]; b2z = b2[1024 + c]; b2n = b2[2048 + c];
    }

    float hreg1[4] = {0.f, 0.f, 0.f, 0.f};
    float hreg2[4] = {0.f, 0.f, 0.f, 0.f};

    // prefetch gx1 + pad for s=0
    float gxv[12]; float4 pv1;
    #pragma unroll
    for (int r = 0; r < 4; ++r) {
        size_t o = (size_t)(bq + r) * 3072 + c0 + (ml & 7);
        gxv[r * 3 + 0] = (float)gx1[o];
        gxv[r * 3 + 1] = (float)gx1[o + 1024];
        gxv[r * 3 + 2] = (float)gx1[o + 2048];
    }
    pv1 = *(const float4*)(pad + bq);

    for (int s = 0; s < 514; ++s) {
        const int t2 = s - 2;

        // ---- pre-poll work: gx2 tiles from h1[s-2] (stable since beat s-1)
        f32x4 g2t1 = {0,0,0,0}, g2t2 = {0,0,0,0};
        if (s >= 2)
            mm(lds, 1, h1buf + (size_t)(s - 2) * 65536, myrow, ml, kb16, g2t1, g2t2);

        // ---- poll: all blocks finished beat s-1
        if (s > 0) {
            unsigned tgt = (unsigned)s;
            while (true) {
                unsigned fa = __hip_atomic_load(fb + lane, __ATOMIC_RELAXED,
                                                __HIP_MEMORY_SCOPE_AGENT);
                unsigned fc = __hip_atomic_load(fb + 64 + lane, __ATOMIC_RELAXED,
                                                __HIP_MEMORY_SCOPE_AGENT);
                if (__all((int)(fa >= tgt && fc >= tgt))) break;
                __builtin_amdgcn_s_sleep(1);
            }
            asm volatile("" ::: "memory");
        }

        // ================ phase B: layer-2 step t2 (s >= 2) ================
        if (s >= 2) {
            f32x4 h2t1 = {0,0,0,0}, h2t2 = {0,0,0,0};
            if (s >= 3)
                mm(lds, 2, hs2 + (size_t)(t2 - 1) * 65536, myrow, ml, kb16, h2t1, h2t2);
            float gr[4], gz[4], gn[4];
            #pragma unroll
            for (int r = 0; r < 4; ++r) {
                gr[r] = g2t1[r] + b2r;
                gz[r] = __shfl_xor(g2t1[r], 8, 64) + b2z;
                gn[r] = g2t2[r] + b2n;
            }
            float4 pv2 = *(const float4*)(pad + t2 * 64 + bq);
            do_gates(gr, gz, gn, h2t1, h2t2, pv2, hreg2,
                     hs2 + (size_t)t2 * 65536, bq, c0, ml);
        }

        // ================ phase A: layer-1 step s (s < 512) ================
        if (s < 512) {
            f32x4 at1 = {0,0,0,0}, at2 = {0,0,0,0};
            if (s > 0)
                mm(lds, 0, h1buf + (size_t)(s - 1) * 65536, myrow, ml, kb16, at1, at2);
            float gr[4], gz[4], gn[4];
            #pragma unroll
            for (int r = 0; r < 4; ++r) {
                gr[r] = gxv[r * 3 + 0];
                gz[r] = gxv[r * 3 + 1];
                gn[r] = gxv[r * 3 + 2];
            }
            do_gates(gr, gz, gn, at1, at2, pv1, hreg1,
                     h1buf + (size_t)s * 65536, bq, c0, ml);
        }

        // ---- drain h stores, block arrive, publish; then prefetch next gx
        asm volatile("s_waitcnt vmcnt(0)" ::: "memory");
        __syncthreads();
        if (tid == 0)
            __hip_atomic_store(fb + blockIdx.x, (unsigned)(s + 1),
                               __ATOMIC_RELAXED, __HIP_MEMORY_SCOPE_AGENT);
        if (s < 511) {   // prefetch gx1[s+1] + pad (overlaps next beat's poll)
            int tn = s + 1;
            const bf16* gxt = gx1 + (size_t)tn * 196608;
            #pragma unroll
            for (int r = 0; r < 4; ++r) {
                size_t o = (size_t)(bq + r) * 3072 + c0 + (ml & 7);
                gxv[r * 3 + 0] = (float)gxt[o];
                gxv[r * 3 + 1] = (float)gxt[o + 1024];
                gxv[r * 3 + 2] = (float)gxt[o + 2048];
            }
            pv1 = *(const float4*)(pad + tn * 64 + bq);
        }
    }
}

// ---------------------------------------------------------------------------
extern "C" void kernel_launch(void* const* d_in, const int* in_sizes, int n_in,
                              void* d_out, int out_size, void* d_ws, size_t ws_size,
                              hipStream_t stream) {
    const float* x    = (const float*)d_in[0];
    const float* pad  = (const float*)d_in[1];
    const float* Wih1 = (const float*)d_in[2];
    const float* Whh1 = (const float*)d_in[3];
    const float* b1   = (const float*)d_in[4];
    const float* Who1 = (const float*)d_in[5];
    const float* Wih2 = (const float*)d_in[6];
    const float* Whh2 = (const float*)d_in[7];
    const float* b2   = (const float*)d_in[8];
    const float* Who2 = (const float*)d_in[9];
    float* out_f = (float*)d_out;

    char* p = (char*)d_ws;
    bf16* xb    = (bf16*)p; p += (size_t)32768 * 1024 * 2;  //  64MB
    bf16* gxb   = (bf16*)p; p += (size_t)32768 * 3072 * 2;  // 192MB (gx1)
    bf16* h1buf = (bf16*)p; p += (size_t)32768 * 1024 * 2;  //  64MB
    bf16* hs2   = (bf16*)p; p += (size_t)32768 * 1024 * 2;  //  64MB
    bf16* WT1   = (bf16*)p; p += (size_t)3072 * 1024 * 2;   //   6MB
    bf16* who1b = (bf16*)p; p += (size_t)1024 * 1024 * 2;   //   2MB
    bf16* W2fT  = (bf16*)p; p += (size_t)3072 * 1024 * 2;   //   6MB
    bf16* WH1   = (bf16*)p; p += (size_t)3072 * 1024 * 2;   //   6MB
    bf16* WH2   = (bf16*)p; p += (size_t)3072 * 1024 * 2;   //   6MB
    unsigned* fb = (unsigned*)p; p += 1024;

    hipFuncSetAttribute((const void*)gru_merged,
                        hipFuncAttributeMaxDynamicSharedMemorySize, LDS_TOT);

    // 1. x -> bf16
    cast_f32_bf16<<<16384, 256, 0, stream>>>(x, xb);
    // 2. gx1 = x @ Wih1 + b1
    transpose_cast<<<dim3(96, 32), 256, 0, stream>>>(Wih1, WT1, 1024, 3072);
    gemm128<true, true><<<dim3(24, 256), 256, 0, stream>>>(
        xb, WT1, b1, gxb, 32768, 3072, 1024);
    // 3. W2fT = (Who1 @ Wih2)^T  (r5/r7/r8-verified recipe)
    transpose_cast<<<dim3(96, 32), 256, 0, stream>>>(Wih2, WT1, 1024, 3072);
    cast_f32_bf16<<<512, 256, 0, stream>>>(Who1, who1b);
    gemm128<true, false><<<dim3(8, 24), 256, 0, stream>>>(
        WT1, who1b, nullptr, W2fT, 3072, 1024, 1024);
    // 4. recurrent weights; Who2T into WT1 (stream-ordered reuse)
    transpose_cast<<<dim3(96, 32), 256, 0, stream>>>(Whh1, WH1, 1024, 3072);
    transpose_cast<<<dim3(96, 32), 256, 0, stream>>>(Whh2, WH2, 1024, 3072);
    transpose_cast<<<dim3(32, 32), 256, 0, stream>>>(Who2, WT1, 1024, 1024);
    hipMemsetAsync(fb, 0, 1024, stream);
    // 5. merged lag-2 two-layer scan
    gru_merged<<<128, 256, LDS_TOT, stream>>>(WH1, W2fT, WH2, gxb, pad, b2,
                                              h1buf, hs2, fb);
    // 6. out = hs2 @ Who2 (f32)
    gemm128<false, false><<<dim3(8, 256), 256, 0, stream>>>(
        hs2, WT1, nullptr, out_f, 32768, 1024, 1024);
}

// Round 14
// 8489.010 us; speedup vs baseline: 1.1158x; 1.1158x over previous
//
#include <hip/hip_runtime.h>
#include <hip/hip_bf16.h>

typedef __bf16 bf16;
typedef __bf16 bf16x8 __attribute__((ext_vector_type(8)));
typedef float  f32x4  __attribute__((ext_vector_type(4)));

#define SLICE2  49152               // 24-row x 2KB weight slice (role2)
#define ZOFF2   (2 * SLICE2)        // zero rows for role2 pad tile
#define LDS_TOT (2 * SLICE2 + 2048) // 100352 B (role0 uses 98304 of it)

// ---------------------------------------------------------------------------
__global__ __launch_bounds__(256) void cast_f32_bf16(const float* __restrict__ in,
                                                     bf16* __restrict__ out) {
    size_t i = ((size_t)blockIdx.x * blockDim.x + threadIdx.x) * 8;
    float4 a = *(const float4*)(in + i);
    float4 b = *(const float4*)(in + i + 4);
    bf16x8 o;
    o[0] = (bf16)a.x; o[1] = (bf16)a.y; o[2] = (bf16)a.z; o[3] = (bf16)a.w;
    o[4] = (bf16)b.x; o[5] = (bf16)b.y; o[6] = (bf16)b.z; o[7] = (bf16)b.w;
    *(bf16x8*)(out + i) = o;
}

// ---------------------------------------------------------------------------
__global__ __launch_bounds__(256) void transpose_cast(const float* __restrict__ in,
                                                      bf16* __restrict__ out,
                                                      int R, int C) {
    __shared__ float tile[32][33];
    int c0 = blockIdx.x * 32, r0 = blockIdx.y * 32;
    int tx = threadIdx.x & 31, ty = threadIdx.x >> 5;
    #pragma unroll
    for (int i = 0; i < 32; i += 8)
        tile[ty + i][tx] = in[(size_t)(r0 + ty + i) * C + c0 + tx];
    __syncthreads();
    #pragma unroll
    for (int i = 0; i < 32; i += 8)
        out[(size_t)(c0 + ty + i) * R + r0 + tx] = (bf16)tile[tx][ty + i];
}

// ---------------------------------------------------------------------------
template<bool BF16_OUT, bool HAS_BIAS>
__global__ __launch_bounds__(256) void gemm128(const bf16* __restrict__ A,
                                               const bf16* __restrict__ Bt,
                                               const float* __restrict__ bias,
                                               void* __restrict__ Cout,
                                               int M, int N, int K) {
    __shared__ bf16 sA[128][72];
    __shared__ bf16 sB[128][72];
    const int tid = threadIdx.x, lane = tid & 63, w = tid >> 6;
    const int wr = w >> 1, wc = w & 1;
    const int m0 = blockIdx.y * 128, n0 = blockIdx.x * 128;
    const int ml = lane & 15, kb = (lane >> 4) * 8;

    f32x4 acc[4][4] = {};
    const bf16* Ab = A  + (size_t)m0 * K;
    const bf16* Bb = Bt + (size_t)n0 * K;

    for (int kc = 0; kc < K; kc += 64) {
        #pragma unroll
        for (int i = 0; i < 4; ++i) {
            int c = tid + 256 * i;
            int row = c >> 3, col = (c & 7) * 8;
            *(uint4*)&sA[row][col] = *(const uint4*)(Ab + (size_t)row * K + kc + col);
            *(uint4*)&sB[row][col] = *(const uint4*)(Bb + (size_t)row * K + kc + col);
        }
        __syncthreads();
        #pragma unroll
        for (int ks = 0; ks < 2; ++ks) {
            bf16x8 af[4], bfr[4];
            #pragma unroll
            for (int i = 0; i < 4; ++i)
                af[i] = *(const bf16x8*)&sA[wr * 64 + i * 16 + ml][ks * 32 + kb];
            #pragma unroll
            for (int i = 0; i < 4; ++i)
                bfr[i] = *(const bf16x8*)&sB[wc * 64 + i * 16 + ml][ks * 32 + kb];
            #pragma unroll
            for (int mi = 0; mi < 4; ++mi)
                #pragma unroll
                for (int ni = 0; ni < 4; ++ni)
                    acc[mi][ni] = __builtin_amdgcn_mfma_f32_16x16x32_bf16(
                        af[mi], bfr[ni], acc[mi][ni], 0, 0, 0);
        }
        __syncthreads();
    }
    const int rbase = (lane >> 4) * 4;
    #pragma unroll
    for (int mi = 0; mi < 4; ++mi) {
        #pragma unroll
        for (int ni = 0; ni < 4; ++ni) {
            int col = n0 + wc * 64 + ni * 16 + ml;
            float bv = HAS_BIAS ? bias[col] : 0.f;
            #pragma unroll
            for (int r = 0; r < 4; ++r) {
                int row = m0 + wr * 64 + mi * 16 + rbase + r;
                float v = acc[mi][ni][r] + bv;
                if constexpr (BF16_OUT)
                    ((bf16*)Cout)[(size_t)row * N + col] = (bf16)v;
                else
                    ((float*)Cout)[(size_t)row * N + col] = v;
            }
        }
    }
}

// ---------------------------------------------------------------------------
// role0 pass: 16 h-rows x K=1024 against a 48-row LDS slice -> acc[3] (r8).
__device__ __forceinline__ void mm48(const char* sW, const bf16* hsrc,
                                     int myrow, int kb, int ml, f32x4 acc[3]) {
    const char* rowp = (const char*)(hsrc + (size_t)myrow * 1024) + kb * 2;
    uint4 hq[32];
    #pragma unroll
    for (int ks = 0; ks < 32; ++ks)
        asm volatile("global_load_dwordx4 %0, %1, off"
                     : "=v"(hq[ks]) : "v"(rowp + ks * 64) : "memory");
    asm volatile("s_waitcnt vmcnt(16)" ::: "memory");
    __builtin_amdgcn_sched_barrier(0);
    #pragma unroll
    for (int ks = 0; ks < 16; ++ks) {
        bf16x8 af = __builtin_bit_cast(bf16x8, hq[ks]);
        #pragma unroll
        for (int g = 0; g < 3; ++g) {
            int brow = g * 16 + ml;
            int addr = brow * 2048 + (ks * 32 + kb) * 2;
            addr ^= (brow & 7) << 4;
            bf16x8 bw = *(const bf16x8*)(sW + addr);
            acc[g] = __builtin_amdgcn_mfma_f32_16x16x32_bf16(af, bw, acc[g], 0, 0, 0);
        }
    }
    asm volatile("s_waitcnt vmcnt(0)" ::: "memory");
    __builtin_amdgcn_sched_barrier(0);
    #pragma unroll
    for (int ks = 16; ks < 32; ++ks) {
        bf16x8 af = __builtin_bit_cast(bf16x8, hq[ks]);
        #pragma unroll
        for (int g = 0; g < 3; ++g) {
            int brow = g * 16 + ml;
            int addr = brow * 2048 + (ks * 32 + kb) * 2;
            addr ^= (brow & 7) << 4;
            bf16x8 bw = *(const bf16x8*)(sW + addr);
            acc[g] = __builtin_amdgcn_mfma_f32_16x16x32_bf16(af, bw, acc[g], 0, 0, 0);
        }
    }
}

// role2 pass: 16 h-rows x K=1024 against one 24-row LDS slice (r12 layout).
__device__ __forceinline__ void mm24(const char* lds, int mat, const bf16* hsrc,
                                     int myrow, int ml, int kb16,
                                     f32x4& t1, f32x4& t2) {
    const char* rowp = (const char*)(hsrc + (size_t)myrow * 1024) + kb16;
    uint4 q[32];
    #pragma unroll
    for (int ks = 0; ks < 32; ++ks)
        asm volatile("global_load_dwordx4 %0, %1, off"
                     : "=v"(q[ks]) : "v"(rowp + ks * 64) : "memory");
    asm volatile("s_waitcnt vmcnt(0)" ::: "memory");
    __builtin_amdgcn_sched_barrier(0);

    const char* base = lds + mat * SLICE2;
    const char* r1 = base + ml * 2048;
    const char* r2 = (ml < 8) ? (base + (16 + ml) * 2048) : (lds + ZOFF2);
    const int sw = (ml & 7) << 4;
    #pragma unroll
    for (int ks = 0; ks < 32; ++ks) {
        bf16x8 af = __builtin_bit_cast(bf16x8, q[ks]);
        int ko = ks * 64 + kb16;
        bf16x8 bw1 = *(const bf16x8*)(r1 + (ko ^ sw));
        bf16x8 bw2 = *(const bf16x8*)(r2 + (ko ^ sw));
        t1 = __builtin_amdgcn_mfma_f32_16x16x32_bf16(af, bw1, t1, 0, 0, 0);
        t2 = __builtin_amdgcn_mfma_f32_16x16x32_bf16(af, bw2, t2, 0, 0, 0);
    }
}

__device__ __forceinline__ void store_pair_sc(bf16* base, size_t idx,
                                              unsigned short v, int ml) {
    unsigned nb = (unsigned)__shfl_xor((int)(unsigned)v, 1, 64);
    if ((ml & 1) == 0) {
        unsigned pk = (unsigned)v | (nb << 16);
        __hip_atomic_store((unsigned*)(base + idx), pk,
                           __ATOMIC_RELAXED, __HIP_MEMORY_SCOPE_AGENT);
    }
}

// role2 gates (8-col dual-tile layout, r12): lanes ml<8 own col c0+ml, 4 rows.
__device__ __forceinline__ void do_gates8(const float gr[4], const float gz[4],
                                          const float gn[4], f32x4 ht1, f32x4 ht2,
                                          float4 pv, float hreg[4],
                                          bf16* dst, int bq, int c0, int ml) {
    unsigned short hpk[4];
    #pragma unroll
    for (int r = 0; r < 4; ++r) {
        float ghr = ht1[r];
        float ghz = __shfl_xor(ht1[r], 8, 64);
        float ghn = ht2[r];
        float rr = 1.f / (1.f + __expf(-(gr[r] + ghr)));
        float zz = 1.f / (1.f + __expf(-(gz[r] + ghz)));
        float nn = tanhf(gn[r] + rr * ghn);
        float hold = hreg[r];
        float hn = (1.f - zz) * nn + zz * hold;
        float p = (r == 0) ? pv.x : (r == 1) ? pv.y : (r == 2) ? pv.z : pv.w;
        hn = p * hold + (1.f - p) * hn;
        hreg[r] = hn;
        hpk[r] = __builtin_bit_cast(unsigned short, (bf16)hn);
    }
    #pragma unroll
    for (int r = 0; r < 4; ++r) {
        unsigned nb = (unsigned)__shfl_xor((int)(unsigned)hpk[r], 1, 64);
        if ((ml & 1) == 0 && ml < 8) {
            unsigned pk = (unsigned)hpk[r] | (nb << 16);
            __hip_atomic_store((unsigned*)(dst + (size_t)(bq + r) * 1024 + c0 + ml), pk,
                               __ATOMIC_RELAXED, __HIP_MEMORY_SCOPE_AGENT);
        }
    }
}

__device__ __forceinline__ void poll1(const unsigned* a, unsigned ta, int lane) {
    while (true) {
        unsigned fa = __hip_atomic_load(a + lane, __ATOMIC_RELAXED, __HIP_MEMORY_SCOPE_AGENT);
        if (__all((int)(fa >= ta))) break;
        __builtin_amdgcn_s_sleep(1);
    }
    asm volatile("" ::: "memory");
}

__device__ __forceinline__ void publish(unsigned* slot, unsigned val, int lane) {
    asm volatile("s_waitcnt vmcnt(0)" ::: "memory");
    if (lane == 0)
        __hip_atomic_store(slot, val, __ATOMIC_RELAXED, __HIP_MEMORY_SCOPE_AGENT);
}

// ---------------------------------------------------------------------------
// 2-stage fused 2-layer GRU pipeline, 192 blocks x 256 thr:
//  role 0 (blk 0..63, 16 cols):  layer-1 scan -> h1[t]  (r8-proven structure)
//  role 2 (blk 64..191, 8 cols): gx2 = h1[t]@W2f in-register + gh2 =
//        hs2[t-1]@Whh2 + gates -> hs2[t]  (r12-proven machinery)
// Sync: f1 = per-wave 64-flag groups (role0); f3 = per-block 128 flags
// (role2). No rings, no back-pressure, unconditional publish -> deadlock-free,
// no placement assumptions. h reads cached (fresh addrs), stores sc.
__global__ __launch_bounds__(256, 1) void gru_fused2(
    const bf16* __restrict__ WH1T, const bf16* __restrict__ W2fT,
    const bf16* __restrict__ WH2T, const bf16* __restrict__ gx1,
    const float* __restrict__ pad, const float* __restrict__ b2,
    bf16* __restrict__ h1buf,   // [512][64][1024]
    bf16* __restrict__ hs2,     // [512][64][1024]
    unsigned* __restrict__ f1,  // [256]
    unsigned* __restrict__ f3) { // [128]
    extern __shared__ __align__(16) char lds[];
    const int tid = threadIdx.x, lane = tid & 63, wv = tid >> 6;
    const int ml = lane & 15;
    const int kb = (lane >> 4) * 8;       // K elem offset (role0 convention)
    const int kb16 = kb * 2;              // byte form (role2 convention)
    const int rbase = (lane >> 4) * 4;
    const int myrow = wv * 16 + ml;
    const int bq = wv * 16 + rbase;

    if (blockIdx.x < 64) {
        // ======================= role 0: layer-1 scan =======================
        const int jg = blockIdx.x, j0 = jg * 16, jml = j0 + ml;
        #pragma unroll 1
        for (int i = 0; i < 24; ++i) {
            int c = tid + 256 * i;            // 6144 chunks of 16B
            int rr = c >> 7;                  // 0..47
            int off = (c & 127) * 16;
            int gate = rr >> 4, j = rr & 15;
            const bf16* src = WH1T + (size_t)(gate * 1024 + j0 + j) * 1024 + off / 2;
            *(uint4*)(lds + rr * 2048 + (off ^ ((rr & 7) << 4))) = *(const uint4*)src;
        }
        __syncthreads();

        unsigned* fown = f1 + wv * 64;
        float hreg[4] = {0.f, 0.f, 0.f, 0.f};
        float gxv[12]; float4 pv;
        #pragma unroll
        for (int r = 0; r < 4; ++r) {
            size_t b = (size_t)(bq + r);
            gxv[r * 3 + 0] = (float)gx1[b * 3072 + jml];
            gxv[r * 3 + 1] = (float)gx1[b * 3072 + 1024 + jml];
            gxv[r * 3 + 2] = (float)gx1[b * 3072 + 2048 + jml];
        }
        pv = *(const float4*)(pad + bq);

        for (int t = 0; t < 512; ++t) {
            f32x4 acc[3] = {};
            if (t > 0) {
                poll1(fown, (unsigned)t, lane);
                mm48(lds, h1buf + (size_t)(t - 1) * 65536, myrow, kb, ml, acc);
            }
            unsigned short hpk[4];
            #pragma unroll
            for (int r = 0; r < 4; ++r) {
                float rr = 1.f / (1.f + __expf(-(gxv[r * 3 + 0] + acc[0][r])));
                float zz = 1.f / (1.f + __expf(-(gxv[r * 3 + 1] + acc[1][r])));
                float nn = tanhf(gxv[r * 3 + 2] + rr * acc[2][r]);
                float hold = hreg[r];
                float hn = (1.f - zz) * nn + zz * hold;
                float p = (r == 0) ? pv.x : (r == 1) ? pv.y : (r == 2) ? pv.z : pv.w;
                hn = p * hold + (1.f - p) * hn;
                hreg[r] = hn;
                hpk[r] = __builtin_bit_cast(unsigned short, (bf16)hn);
            }
            bf16* hst = h1buf + (size_t)t * 65536;
            #pragma unroll
            for (int r = 0; r < 4; ++r)
                store_pair_sc(hst, (size_t)(bq + r) * 1024 + jml, hpk[r], ml);
            publish(fown + jg, (unsigned)(t + 1), lane);
            {   // prefetch gx1 + pad for t+1 (cached)
                int tn = (t < 511) ? t + 1 : 511;
                const bf16* gxt = gx1 + (size_t)tn * 196608;
                #pragma unroll
                for (int r = 0; r < 4; ++r) {
                    size_t b = (size_t)(bq + r);
                    gxv[r * 3 + 0] = (float)gxt[b * 3072 + jml];
                    gxv[r * 3 + 1] = (float)gxt[b * 3072 + 1024 + jml];
                    gxv[r * 3 + 2] = (float)gxt[b * 3072 + 2048 + jml];
                }
                pv = *(const float4*)(pad + tn * 64 + bq);
            }
        }
    } else {
        // ======================= role 2: layer-2 scan =======================
        const int j2 = blockIdx.x - 64;       // 0..127
        const int c0 = j2 * 8;
        // stage W2fT (mat 0) and WH2T (mat 1), 24 rows each, + zero rows
        #pragma unroll 1
        for (int i = 0; i < 24; ++i) {
            int c = tid + 256 * i;            // 6144 chunks of 16B
            int row = c >> 7;                 // 0..47
            int off = (c & 127) * 16;
            int mat = (row >= 24);
            int sr = row - mat * 24;
            int gate = sr >> 3, cx = sr & 7;
            const bf16* Wsrc = mat ? WH2T : W2fT;
            const bf16* src = Wsrc + (size_t)(gate * 1024 + c0 + cx) * 1024 + off / 2;
            *(uint4*)(lds + mat * SLICE2 + sr * 2048 + (off ^ ((sr & 7) << 4))) =
                *(const uint4*)src;
        }
        if (tid < 128) { uint4 z = {0, 0, 0, 0}; *(uint4*)(lds + ZOFF2 + tid * 16) = z; }
        __syncthreads();

        float b2r, b2z, b2n;
        {
            int c = c0 + (ml & 7);
            b2r = b2[c]; b2z = b2[1024 + c]; b2n = b2[2048 + c];
        }
        float hreg2[4] = {0.f, 0.f, 0.f, 0.f};

        for (int t = 0; t < 512; ++t) {
            // poll: role0 finished t (f1 >= t+1) AND all role2 finished t-1
            {
                unsigned t1v = (unsigned)(t + 1), t0v = (unsigned)t;
                const unsigned* fa = f1 + wv * 64;
                while (true) {
                    unsigned a = __hip_atomic_load(fa + lane, __ATOMIC_RELAXED,
                                                   __HIP_MEMORY_SCOPE_AGENT);
                    unsigned c = __hip_atomic_load(f3 + lane, __ATOMIC_RELAXED,
                                                   __HIP_MEMORY_SCOPE_AGENT);
                    unsigned d = __hip_atomic_load(f3 + 64 + lane, __ATOMIC_RELAXED,
                                                   __HIP_MEMORY_SCOPE_AGENT);
                    if (__all((int)(a >= t1v && c >= t0v && d >= t0v))) break;
                    __builtin_amdgcn_s_sleep(1);
                }
                asm volatile("" ::: "memory");
            }

            f32x4 g1 = {0,0,0,0}, g2 = {0,0,0,0};     // gx2 tiles [r|z],[n|pad]
            f32x4 h1t = {0,0,0,0}, h2t = {0,0,0,0};   // gh2 tiles
            mm24(lds, 0, h1buf + (size_t)t * 65536, myrow, ml, kb16, g1, g2);
            if (t > 0)
                mm24(lds, 1, hs2 + (size_t)(t - 1) * 65536, myrow, ml, kb16, h1t, h2t);

            float gr[4], gz[4], gn[4];
            #pragma unroll
            for (int r = 0; r < 4; ++r) {
                gr[r] = g1[r] + b2r;
                gz[r] = __shfl_xor(g1[r], 8, 64) + b2z;
                gn[r] = g2[r] + b2n;
            }
            float4 pvx = *(const float4*)(pad + t * 64 + bq);
            do_gates8(gr, gz, gn, h1t, h2t, pvx, hreg2,
                      hs2 + (size_t)t * 65536, bq, c0, ml);

            asm volatile("s_waitcnt vmcnt(0)" ::: "memory");
            __syncthreads();
            if (tid == 0)
                __hip_atomic_store(f3 + j2, (unsigned)(t + 1),
                                   __ATOMIC_RELAXED, __HIP_MEMORY_SCOPE_AGENT);
        }
    }
}

// ---------------------------------------------------------------------------
extern "C" void kernel_launch(void* const* d_in, const int* in_sizes, int n_in,
                              void* d_out, int out_size, void* d_ws, size_t ws_size,
                              hipStream_t stream) {
    const float* x    = (const float*)d_in[0];
    const float* pad  = (const float*)d_in[1];
    const float* Wih1 = (const float*)d_in[2];
    const float* Whh1 = (const float*)d_in[3];
    const float* b1   = (const float*)d_in[4];
    const float* Who1 = (const float*)d_in[5];
    const float* Wih2 = (const float*)d_in[6];
    const float* Whh2 = (const float*)d_in[7];
    const float* b2   = (const float*)d_in[8];
    const float* Who2 = (const float*)d_in[9];
    float* out_f = (float*)d_out;

    char* p = (char*)d_ws;
    bf16* xb    = (bf16*)p; p += (size_t)32768 * 1024 * 2;  //  64MB
    bf16* gxb   = (bf16*)p; p += (size_t)32768 * 3072 * 2;  // 192MB (gx1)
    bf16* h1buf = (bf16*)p; p += (size_t)32768 * 1024 * 2;  //  64MB
    bf16* hs2   = (bf16*)p; p += (size_t)32768 * 1024 * 2;  //  64MB
    bf16* WT1   = (bf16*)p; p += (size_t)3072 * 1024 * 2;   //   6MB
    bf16* who1b = (bf16*)p; p += (size_t)1024 * 1024 * 2;   //   2MB
    bf16* W2fT  = (bf16*)p; p += (size_t)3072 * 1024 * 2;   //   6MB
    bf16* WH1   = (bf16*)p; p += (size_t)3072 * 1024 * 2;   //   6MB
    bf16* WH2   = (bf16*)p; p += (size_t)3072 * 1024 * 2;   //   6MB
    unsigned* flags = (unsigned*)p; p += 4096;
    unsigned* f1 = flags, * f3 = flags + 256;

    hipFuncSetAttribute((const void*)gru_fused2,
                        hipFuncAttributeMaxDynamicSharedMemorySize, 131072);

    // 1. x -> bf16
    cast_f32_bf16<<<16384, 256, 0, stream>>>(x, xb);
    // 2. gx1 = x @ Wih1 + b1
    transpose_cast<<<dim3(96, 32), 256, 0, stream>>>(Wih1, WT1, 1024, 3072);
    gemm128<true, true><<<dim3(24, 256), 256, 0, stream>>>(
        xb, WT1, b1, gxb, 32768, 3072, 1024);
    // 3. W2fT = (Who1 @ Wih2)^T  (verified recipe)
    transpose_cast<<<dim3(96, 32), 256, 0, stream>>>(Wih2, WT1, 1024, 3072);
    cast_f32_bf16<<<512, 256, 0, stream>>>(Who1, who1b);
    gemm128<true, false><<<dim3(8, 24), 256, 0, stream>>>(
        WT1, who1b, nullptr, W2fT, 3072, 1024, 1024);
    // 4. recurrent weights; Who2T into WT1 (stream-ordered reuse)
    transpose_cast<<<dim3(96, 32), 256, 0, stream>>>(Whh1, WH1, 1024, 3072);
    transpose_cast<<<dim3(96, 32), 256, 0, stream>>>(Whh2, WH2, 1024, 3072);
    transpose_cast<<<dim3(32, 32), 256, 0, stream>>>(Who2, WT1, 1024, 1024);
    hipMemsetAsync(flags, 0, 4096, stream);
    // 5. fused 2-stage pipelined scan
    gru_fused2<<<192, 256, LDS_TOT, stream>>>(WH1, W2fT, WH2, gxb, pad, b2,
                                              h1buf, hs2, f1, f3);
    // 6. out = hs2 @ Who2 (f32)
    gemm128<false, false><<<dim3(8, 256), 256, 0, stream>>>(
        hs2, WT1, nullptr, out_f, 32768, 1024, 1024);
}

// Round 15
// 5346.988 us; speedup vs baseline: 1.7714x; 1.5876x over previous
//
#include <hip/hip_runtime.h>
#include <hip/hip_bf16.h>

typedef __bf16 bf16;
typedef __bf16 bf16x8 __attribute__((ext_vector_type(8)));
typedef float  f32x4  __attribute__((ext_vector_type(4)));
typedef unsigned long long u64;

// ---------------------------------------------------------------------------
__global__ __launch_bounds__(256) void cast_f32_bf16(const float* __restrict__ in,
                                                     bf16* __restrict__ out) {
    size_t i = ((size_t)blockIdx.x * blockDim.x + threadIdx.x) * 8;
    float4 a = *(const float4*)(in + i);
    float4 b = *(const float4*)(in + i + 4);
    bf16x8 o;
    o[0] = (bf16)a.x; o[1] = (bf16)a.y; o[2] = (bf16)a.z; o[3] = (bf16)a.w;
    o[4] = (bf16)b.x; o[5] = (bf16)b.y; o[6] = (bf16)b.z; o[7] = (bf16)b.w;
    *(bf16x8*)(out + i) = o;
}

// ---------------------------------------------------------------------------
__global__ __launch_bounds__(256) void transpose_cast(const float* __restrict__ in,
                                                      bf16* __restrict__ out,
                                                      int R, int C) {
    __shared__ float tile[32][33];
    int c0 = blockIdx.x * 32, r0 = blockIdx.y * 32;
    int tx = threadIdx.x & 31, ty = threadIdx.x >> 5;
    #pragma unroll
    for (int i = 0; i < 32; i += 8)
        tile[ty + i][tx] = in[(size_t)(r0 + ty + i) * C + c0 + tx];
    __syncthreads();
    #pragma unroll
    for (int i = 0; i < 32; i += 8)
        out[(size_t)(c0 + ty + i) * R + r0 + tx] = (bf16)tile[tx][ty + i];
}

// ---------------------------------------------------------------------------
template<bool BF16_OUT, bool HAS_BIAS>
__global__ __launch_bounds__(256) void gemm128(const bf16* __restrict__ A,
                                               const bf16* __restrict__ Bt,
                                               const float* __restrict__ bias,
                                               void* __restrict__ Cout,
                                               int M, int N, int K) {
    __shared__ bf16 sA[128][72];
    __shared__ bf16 sB[128][72];
    const int tid = threadIdx.x, lane = tid & 63, w = tid >> 6;
    const int wr = w >> 1, wc = w & 1;
    const int m0 = blockIdx.y * 128, n0 = blockIdx.x * 128;
    const int ml = lane & 15, kb = (lane >> 4) * 8;

    f32x4 acc[4][4] = {};
    const bf16* Ab = A  + (size_t)m0 * K;
    const bf16* Bb = Bt + (size_t)n0 * K;

    for (int kc = 0; kc < K; kc += 64) {
        #pragma unroll
        for (int i = 0; i < 4; ++i) {
            int c = tid + 256 * i;
            int row = c >> 3, col = (c & 7) * 8;
            *(uint4*)&sA[row][col] = *(const uint4*)(Ab + (size_t)row * K + kc + col);
            *(uint4*)&sB[row][col] = *(const uint4*)(Bb + (size_t)row * K + kc + col);
        }
        __syncthreads();
        #pragma unroll
        for (int ks = 0; ks < 2; ++ks) {
            bf16x8 af[4], bfr[4];
            #pragma unroll
            for (int i = 0; i < 4; ++i)
                af[i] = *(const bf16x8*)&sA[wr * 64 + i * 16 + ml][ks * 32 + kb];
            #pragma unroll
            for (int i = 0; i < 4; ++i)
                bfr[i] = *(const bf16x8*)&sB[wc * 64 + i * 16 + ml][ks * 32 + kb];
            #pragma unroll
            for (int mi = 0; mi < 4; ++mi)
                #pragma unroll
                for (int ni = 0; ni < 4; ++ni)
                    acc[mi][ni] = __builtin_amdgcn_mfma_f32_16x16x32_bf16(
                        af[mi], bfr[ni], acc[mi][ni], 0, 0, 0);
        }
        __syncthreads();
    }
    const int rbase = (lane >> 4) * 4;
    #pragma unroll
    for (int mi = 0; mi < 4; ++mi) {
        #pragma unroll
        for (int ni = 0; ni < 4; ++ni) {
            int col = n0 + wc * 64 + ni * 16 + ml;
            float bv = HAS_BIAS ? bias[col] : 0.f;
            #pragma unroll
            for (int r = 0; r < 4; ++r) {
                int row = m0 + wr * 64 + mi * 16 + rbase + r;
                float v = acc[mi][ni][r] + bv;
                if constexpr (BF16_OUT)
                    ((bf16*)Cout)[(size_t)row * N + col] = (bf16)v;
                else
                    ((float*)Cout)[(size_t)row * N + col] = v;
            }
        }
    }
}

// ---------------------------------------------------------------------------
// [16 rows x 1024] @ [1024 x 48-col LDS slice] -> acc[3] per thread.
// CACHED inline-asm loads, all 32 quads in flight, staged vmcnt(16)/vmcnt(0).
__device__ __forceinline__ void mm_step(const char* sW, const bf16* hsrc,
                                        int myrow, int kb, int ml, f32x4 acc[3]) {
    const char* rowp = (const char*)(hsrc + (size_t)myrow * 1024) + kb * 2;
    uint4 hq[32];
    #pragma unroll
    for (int ks = 0; ks < 32; ++ks)
        asm volatile("global_load_dwordx4 %0, %1, off"
                     : "=v"(hq[ks]) : "v"(rowp + ks * 64) : "memory");
    asm volatile("s_waitcnt vmcnt(16)" ::: "memory");
    __builtin_amdgcn_sched_barrier(0);
    #pragma unroll
    for (int ks = 0; ks < 16; ++ks) {
        bf16x8 af = __builtin_bit_cast(bf16x8, hq[ks]);
        #pragma unroll
        for (int g = 0; g < 3; ++g) {
            int brow = g * 16 + ml;
            int addr = brow * 2048 + (ks * 32 + kb) * 2;
            addr ^= (brow & 7) << 4;
            bf16x8 bw = *(const bf16x8*)(sW + addr);
            acc[g] = __builtin_amdgcn_mfma_f32_16x16x32_bf16(af, bw, acc[g], 0, 0, 0);
        }
    }
    asm volatile("s_waitcnt vmcnt(0)" ::: "memory");
    __builtin_amdgcn_sched_barrier(0);
    #pragma unroll
    for (int ks = 16; ks < 32; ++ks) {
        bf16x8 af = __builtin_bit_cast(bf16x8, hq[ks]);
        #pragma unroll
        for (int g = 0; g < 3; ++g) {
            int brow = g * 16 + ml;
            int addr = brow * 2048 + (ks * 32 + kb) * 2;
            addr ^= (brow & 7) << 4;
            bf16x8 bw = *(const bf16x8*)(sW + addr);
            acc[g] = __builtin_amdgcn_mfma_f32_16x16x32_bf16(af, bw, acc[g], 0, 0, 0);
        }
    }
}

__device__ __forceinline__ void store_pair_sc(bf16* base, size_t idx,
                                              unsigned short v, int ml) {
    unsigned nb = (unsigned)__shfl_xor((int)(unsigned)v, 1, 64);
    if ((ml & 1) == 0) {
        unsigned pk = (unsigned)v | (nb << 16);
        __hip_atomic_store((unsigned*)(base + idx), pk,
                           __ATOMIC_RELAXED, __HIP_MEMORY_SCOPE_AGENT);
    }
}

// coalesced 64-lane polls of monotonic flag groups (s_sleep(4) ~ 0.1us grain)
__device__ __forceinline__ void poll1(const unsigned* a, unsigned ta, int lane) {
    while (true) {
        unsigned fa = __hip_atomic_load(a + lane, __ATOMIC_RELAXED, __HIP_MEMORY_SCOPE_AGENT);
        if (__all((int)(fa >= ta))) break;
        __builtin_amdgcn_s_sleep(4);
    }
    asm volatile("" ::: "memory");
}
__device__ __forceinline__ void poll2(const unsigned* a, unsigned ta,
                                      const unsigned* b, unsigned tb, int lane) {
    while (true) {
        unsigned fa = __hip_atomic_load(a + lane, __ATOMIC_RELAXED, __HIP_MEMORY_SCOPE_AGENT);
        unsigned fb = __hip_atomic_load(b + lane, __ATOMIC_RELAXED, __HIP_MEMORY_SCOPE_AGENT);
        if (__all((int)(fa >= ta && fb >= tb))) break;
        __builtin_amdgcn_s_sleep(4);
    }
    asm volatile("" ::: "memory");
}

__device__ __forceinline__ void publish1(unsigned* s1, unsigned val, int lane) {
    asm volatile("s_waitcnt vmcnt(0)" ::: "memory");
    if (lane == 0)
        __hip_atomic_store(s1, val, __ATOMIC_RELAXED, __HIP_MEMORY_SCOPE_AGENT);
}
__device__ __forceinline__ void publish2(unsigned* s1, unsigned* s2,
                                         unsigned val, int lane) {
    asm volatile("s_waitcnt vmcnt(0)" ::: "memory");
    if (lane == 0) {
        __hip_atomic_store(s1, val, __ATOMIC_RELAXED, __HIP_MEMORY_SCOPE_AGENT);
        __hip_atomic_store(s2, val, __ATOMIC_RELAXED, __HIP_MEMORY_SCOPE_AGENT);
    }
}

// ---------------------------------------------------------------------------
// Fused 2-layer GRU pipeline (r8 structure), 192 blocks x 256 thr:
//  role 0 (blk 0..63):   layer-1 scan -> h1[t]  (full 512-slot buffer)
//  role 1 (blk 64..127): gx2[t] = h1[t] @ W2f   -> 16-slot ring (sc,
//                        TRANSPOSED [g][col][row] so both sides use 8B ops)
//  role 2 (blk 128..191):layer-2 scan -> hs2[t] (full 512-slot buffer)
// MALL-load reduction vs r8: per-consumer flag copies (no line polled by two
// roles), 3x8B gx2 stores/loads per thread (was 6x4B / 12x2B), s_sleep(4).
__global__ __launch_bounds__(256, 1) void gru_fused(
    const bf16* __restrict__ WH1T, const bf16* __restrict__ W2fT,
    const bf16* __restrict__ WH2T, const bf16* __restrict__ gx1,
    const float* __restrict__ pad, const float* __restrict__ b2,
    bf16* __restrict__ h1,       // [512][64][1024]
    bf16* __restrict__ gx2ring,  // 16 x [3][1024][64]  (transposed)
    bf16* __restrict__ hs2,      // [512][64][1024]
    unsigned* __restrict__ f1s, unsigned* __restrict__ f1c,
    unsigned* __restrict__ f2,
    unsigned* __restrict__ f3s, unsigned* __restrict__ f3c) {
    extern __shared__ __align__(16) char sW[];   // 48 x 2048 B, swizzled

    const int tid = threadIdx.x, lane = tid & 63, wv = tid >> 6;
    const int role = blockIdx.x >> 6, jg = blockIdx.x & 63;
    const int j0 = jg * 16;
    const int ml = lane & 15, kb = (lane >> 4) * 8;
    const int rbase = (lane >> 4) * 4;
    const int myrow = wv * 16 + ml;
    const int bbase = wv * 16 + rbase;
    const int jml = j0 + ml;

    // ---- load this role's 48x1024 weight slice into LDS (rows gate*16+j)
    const bf16* Wsrc = (role == 0) ? WH1T : (role == 1) ? W2fT : WH2T;
    #pragma unroll 1
    for (int i = 0; i < 24; ++i) {
        int c = tid + 256 * i;
        int rr = c >> 7;
        int off = (c & 127) * 16;
        int gate = rr >> 4, j = rr & 15;
        const bf16* src = Wsrc + (size_t)(gate * 1024 + j0 + j) * 1024 + off / 2;
        *(uint4*)(sW + rr * 2048 + (off ^ ((rr & 7) << 4))) = *(const uint4*)src;
    }
    __syncthreads();   // sW read-only afterwards; waves free-run

    if (role == 0) {
        // ================= layer-1 scan =================
        unsigned* fown = f1s + wv * 64;
        float hreg[4] = {0.f, 0.f, 0.f, 0.f};
        float gxv[12]; float4 pv;
        #pragma unroll
        for (int r = 0; r < 4; ++r) {
            size_t b = (size_t)(bbase + r);
            gxv[r * 3 + 0] = (float)gx1[b * 3072 + jml];
            gxv[r * 3 + 1] = (float)gx1[b * 3072 + 1024 + jml];
            gxv[r * 3 + 2] = (float)gx1[b * 3072 + 2048 + jml];
        }
        pv = *(const float4*)(pad + bbase);

        for (int t = 0; t < 512; ++t) {
            f32x4 acc[3] = {};
            if (t > 0) {
                poll1(fown, (unsigned)t, lane);
                mm_step(sW, h1 + (size_t)(t - 1) * 65536, myrow, kb, ml, acc);
            }
            unsigned short hpk[4];
            #pragma unroll
            for (int r = 0; r < 4; ++r) {
                float rr = 1.f / (1.f + __expf(-(gxv[r * 3 + 0] + acc[0][r])));
                float zz = 1.f / (1.f + __expf(-(gxv[r * 3 + 1] + acc[1][r])));
                float nn = tanhf(gxv[r * 3 + 2] + rr * acc[2][r]);
                float hold = hreg[r];
                float hn = (1.f - zz) * nn + zz * hold;
                float p = (r == 0) ? pv.x : (r == 1) ? pv.y : (r == 2) ? pv.z : pv.w;
                hn = p * hold + (1.f - p) * hn;
                hreg[r] = hn;
                hpk[r] = __builtin_bit_cast(unsigned short, (bf16)hn);
            }
            bf16* hst = h1 + (size_t)t * 65536;
            #pragma unroll
            for (int r = 0; r < 4; ++r)
                store_pair_sc(hst, (size_t)(bbase + r) * 1024 + jml, hpk[r], ml);
            publish2(fown + jg, f1c + wv * 64 + jg, (unsigned)(t + 1), lane);
            {   // prefetch gx1 + pad for t+1 (cached)
                int tn = (t < 511) ? t + 1 : 511;
                const bf16* gxt = gx1 + (size_t)tn * 64 * 3072;
                #pragma unroll
                for (int r = 0; r < 4; ++r) {
                    size_t b = (size_t)(bbase + r);
                    gxv[r * 3 + 0] = (float)gxt[b * 3072 + jml];
                    gxv[r * 3 + 1] = (float)gxt[b * 3072 + 1024 + jml];
                    gxv[r * 3 + 2] = (float)gxt[b * 3072 + 2048 + jml];
                }
                pv = *(const float4*)(pad + tn * 64 + bbase);
            }
        }
    } else if (role == 1) {
        // ================= gx2 producer =================
        unsigned* fsrc = f1c + wv * 64;
        unsigned* fbp  = f3c + wv * 64;
        for (int t = 0; t < 512; ++t) {
            if (t >= 16) poll2(fsrc, (unsigned)(t + 1), fbp, (unsigned)(t - 15), lane);
            else         poll1(fsrc, (unsigned)(t + 1), lane);
            f32x4 acc[3] = {};
            mm_step(sW, h1 + (size_t)t * 65536, myrow, kb, ml, acc);
            // transposed store: [g][col jml][rows bbase..+3] -> one 8B store per g
            bf16* dst = gx2ring + (size_t)(t & 15) * 196608;
            #pragma unroll
            for (int g = 0; g < 3; ++g) {
                unsigned short w0 = __builtin_bit_cast(unsigned short, (bf16)acc[g][0]);
                unsigned short w1 = __builtin_bit_cast(unsigned short, (bf16)acc[g][1]);
                unsigned short w2 = __builtin_bit_cast(unsigned short, (bf16)acc[g][2]);
                unsigned short w3 = __builtin_bit_cast(unsigned short, (bf16)acc[g][3]);
                u64 pk = (u64)w0 | ((u64)w1 << 16) | ((u64)w2 << 32) | ((u64)w3 << 48);
                __hip_atomic_store((u64*)(dst + ((size_t)(g * 1024 + jml)) * 64 + bbase),
                                   pk, __ATOMIC_RELAXED, __HIP_MEMORY_SCOPE_AGENT);
            }
            publish1(f2 + wv * 64 + jg, (unsigned)(t + 1), lane);
        }
    } else {
        // ================= layer-2 scan =================
        unsigned* fown = f3s + wv * 64;
        unsigned* fgx  = f2 + wv * 64;
        float b2v[3] = {b2[jml], b2[1024 + jml], b2[2048 + jml]};
        float hreg[4] = {0.f, 0.f, 0.f, 0.f};
        float4 pv = *(const float4*)(pad + bbase);

        for (int t = 0; t < 512; ++t) {
            if (t > 0) poll2(fgx, (unsigned)(t + 1), fown, (unsigned)t, lane);
            else       poll1(fgx, 1u, lane);
            // gx2 slice: 3 x 8B sc loads (transposed layout)
            const bf16* gsl = gx2ring + (size_t)(t & 15) * 196608;
            u64 gq[3];
            #pragma unroll
            for (int g = 0; g < 3; ++g)
                gq[g] = __hip_atomic_load(
                    (const u64*)(gsl + ((size_t)(g * 1024 + jml)) * 64 + bbase),
                    __ATOMIC_RELAXED, __HIP_MEMORY_SCOPE_AGENT);
            f32x4 acc[3] = {};
            if (t > 0)
                mm_step(sW, hs2 + (size_t)(t - 1) * 65536, myrow, kb, ml, acc);
            unsigned short hpk[4];
            #pragma unroll
            for (int r = 0; r < 4; ++r) {
                float gr = (float)__builtin_bit_cast(bf16,
                    (unsigned short)(gq[0] >> (r * 16))) + b2v[0];
                float gz = (float)__builtin_bit_cast(bf16,
                    (unsigned short)(gq[1] >> (r * 16))) + b2v[1];
                float gn = (float)__builtin_bit_cast(bf16,
                    (unsigned short)(gq[2] >> (r * 16))) + b2v[2];
                float rr = 1.f / (1.f + __expf(-(gr + acc[0][r])));
                float zz = 1.f / (1.f + __expf(-(gz + acc[1][r])));
                float nn = tanhf(gn + rr * acc[2][r]);
                float hold = hreg[r];
                float hn = (1.f - zz) * nn + zz * hold;
                float p = (r == 0) ? pv.x : (r == 1) ? pv.y : (r == 2) ? pv.z : pv.w;
                hn = p * hold + (1.f - p) * hn;
                hreg[r] = hn;
                hpk[r] = __builtin_bit_cast(unsigned short, (bf16)hn);
            }
            bf16* hst = hs2 + (size_t)t * 65536;
            #pragma unroll
            for (int r = 0; r < 4; ++r)
                store_pair_sc(hst, (size_t)(bbase + r) * 1024 + jml, hpk[r], ml);
            publish2(fown + jg, f3c + wv * 64 + jg, (unsigned)(t + 1), lane);
            int tn = (t < 511) ? t + 1 : 511;
            pv = *(const float4*)(pad + tn * 64 + bbase);
        }
    }
}

// ---------------------------------------------------------------------------
extern "C" void kernel_launch(void* const* d_in, const int* in_sizes, int n_in,
                              void* d_out, int out_size, void* d_ws, size_t ws_size,
                              hipStream_t stream) {
    const float* x    = (const float*)d_in[0];
    const float* pad  = (const float*)d_in[1];
    const float* Wih1 = (const float*)d_in[2];
    const float* Whh1 = (const float*)d_in[3];
    const float* b1   = (const float*)d_in[4];
    const float* Who1 = (const float*)d_in[5];
    const float* Wih2 = (const float*)d_in[6];
    const float* Whh2 = (const float*)d_in[7];
    const float* b2   = (const float*)d_in[8];
    const float* Who2 = (const float*)d_in[9];
    float* out_f = (float*)d_out;

    char* p = (char*)d_ws;
    bf16* xb      = (bf16*)p; p += (size_t)32768 * 1024 * 2;  //  64MB
    bf16* gxb     = (bf16*)p; p += (size_t)32768 * 3072 * 2;  // 192MB (gx1)
    bf16* h1      = (bf16*)p; p += (size_t)32768 * 1024 * 2;  //  64MB
    bf16* hs2     = (bf16*)p; p += (size_t)32768 * 1024 * 2;  //  64MB
    bf16* gx2ring = (bf16*)p; p += (size_t)16 * 196608 * 2;   //   6MB
    bf16* WT1     = (bf16*)p; p += (size_t)3072 * 1024 * 2;   //   6MB
    bf16* who1b   = (bf16*)p; p += (size_t)1024 * 1024 * 2;   //   2MB
    bf16* W2fT    = (bf16*)p; p += (size_t)3072 * 1024 * 2;   //   6MB
    bf16* WH1     = (bf16*)p; p += (size_t)3072 * 1024 * 2;   //   6MB
    bf16* WH2     = (bf16*)p; p += (size_t)3072 * 1024 * 2;   //   6MB
    unsigned* flags = (unsigned*)p; p += 8192;
    unsigned* f1s = flags,        * f1c = flags + 256;
    unsigned* f2  = flags + 512;
    unsigned* f3s = flags + 768,  * f3c = flags + 1024;

    hipFuncSetAttribute((const void*)gru_fused,
                        hipFuncAttributeMaxDynamicSharedMemorySize, 131072);

    // 1. x -> bf16
    cast_f32_bf16<<<16384, 256, 0, stream>>>(x, xb);
    // 2. gx1 = x @ Wih1 + b1
    transpose_cast<<<dim3(96, 32), 256, 0, stream>>>(Wih1, WT1, 1024, 3072);
    gemm128<true, true><<<dim3(24, 256), 256, 0, stream>>>(
        xb, WT1, b1, gxb, 32768, 3072, 1024);
    // 3. W2fT = (Who1 @ Wih2)^T  (verified recipe)
    transpose_cast<<<dim3(96, 32), 256, 0, stream>>>(Wih2, WT1, 1024, 3072);
    cast_f32_bf16<<<512, 256, 0, stream>>>(Who1, who1b);
    gemm128<true, false><<<dim3(8, 24), 256, 0, stream>>>(
        WT1, who1b, nullptr, W2fT, 3072, 1024, 1024);
    // 4. recurrent weights; Who2T into WT1 (stream-ordered reuse)
    transpose_cast<<<dim3(96, 32), 256, 0, stream>>>(Whh1, WH1, 1024, 3072);
    transpose_cast<<<dim3(96, 32), 256, 0, stream>>>(Whh2, WH2, 1024, 3072);
    transpose_cast<<<dim3(32, 32), 256, 0, stream>>>(Who2, WT1, 1024, 1024);
    hipMemsetAsync(flags, 0, 8192, stream);
    // 5. fused pipelined 2-layer scan
    gru_fused<<<192, 256, 98304, stream>>>(WH1, W2fT, WH2, gxb, pad, b2,
                                           h1, gx2ring, hs2,
                                           f1s, f1c, f2, f3s, f3c);
    // 6. out = hs2 @ Who2 (f32)
    gemm128<false, false><<<dim3(8, 256), 256, 0, stream>>>(
        hs2, WT1, nullptr, out_f, 32768, 1024, 1024);
}

// Round 16
// 5226.210 us; speedup vs baseline: 1.8124x; 1.0231x over previous
//
#include <hip/hip_runtime.h>
#include <hip/hip_bf16.h>

typedef __bf16 bf16;
typedef __bf16 bf16x8 __attribute__((ext_vector_type(8)));
typedef float  f32x4  __attribute__((ext_vector_type(4)));
typedef unsigned long long u64;
typedef unsigned short u16;

// ---------------------------------------------------------------------------
__global__ __launch_bounds__(256) void cast_f32_bf16(const float* __restrict__ in,
                                                     bf16* __restrict__ out) {
    size_t i = ((size_t)blockIdx.x * blockDim.x + threadIdx.x) * 8;
    float4 a = *(const float4*)(in + i);
    float4 b = *(const float4*)(in + i + 4);
    bf16x8 o;
    o[0] = (bf16)a.x; o[1] = (bf16)a.y; o[2] = (bf16)a.z; o[3] = (bf16)a.w;
    o[4] = (bf16)b.x; o[5] = (bf16)b.y; o[6] = (bf16)b.z; o[7] = (bf16)b.w;
    *(bf16x8*)(out + i) = o;
}

// ---------------------------------------------------------------------------
__global__ __launch_bounds__(256) void transpose_cast(const float* __restrict__ in,
                                                      bf16* __restrict__ out,
                                                      int R, int C) {
    __shared__ float tile[32][33];
    int c0 = blockIdx.x * 32, r0 = blockIdx.y * 32;
    int tx = threadIdx.x & 31, ty = threadIdx.x >> 5;
    #pragma unroll
    for (int i = 0; i < 32; i += 8)
        tile[ty + i][tx] = in[(size_t)(r0 + ty + i) * C + c0 + tx];
    __syncthreads();
    #pragma unroll
    for (int i = 0; i < 32; i += 8)
        out[(size_t)(c0 + ty + i) * R + r0 + tx] = (bf16)tile[tx][ty + i];
}

// ---------------------------------------------------------------------------
template<bool BF16_OUT, bool HAS_BIAS>
__global__ __launch_bounds__(256) void gemm128(const bf16* __restrict__ A,
                                               const bf16* __restrict__ Bt,
                                               const float* __restrict__ bias,
                                               void* __restrict__ Cout,
                                               int M, int N, int K) {
    __shared__ bf16 sA[128][72];
    __shared__ bf16 sB[128][72];
    const int tid = threadIdx.x, lane = tid & 63, w = tid >> 6;
    const int wr = w >> 1, wc = w & 1;
    const int m0 = blockIdx.y * 128, n0 = blockIdx.x * 128;
    const int ml = lane & 15, kb = (lane >> 4) * 8;

    f32x4 acc[4][4] = {};
    const bf16* Ab = A  + (size_t)m0 * K;
    const bf16* Bb = Bt + (size_t)n0 * K;

    for (int kc = 0; kc < K; kc += 64) {
        #pragma unroll
        for (int i = 0; i < 4; ++i) {
            int c = tid + 256 * i;
            int row = c >> 3, col = (c & 7) * 8;
            *(uint4*)&sA[row][col] = *(const uint4*)(Ab + (size_t)row * K + kc + col);
            *(uint4*)&sB[row][col] = *(const uint4*)(Bb + (size_t)row * K + kc + col);
        }
        __syncthreads();
        #pragma unroll
        for (int ks = 0; ks < 2; ++ks) {
            bf16x8 af[4], bfr[4];
            #pragma unroll
            for (int i = 0; i < 4; ++i)
                af[i] = *(const bf16x8*)&sA[wr * 64 + i * 16 + ml][ks * 32 + kb];
            #pragma unroll
            for (int i = 0; i < 4; ++i)
                bfr[i] = *(const bf16x8*)&sB[wc * 64 + i * 16 + ml][ks * 32 + kb];
            #pragma unroll
            for (int mi = 0; mi < 4; ++mi)
                #pragma unroll
                for (int ni = 0; ni < 4; ++ni)
                    acc[mi][ni] = __builtin_amdgcn_mfma_f32_16x16x32_bf16(
                        af[mi], bfr[ni], acc[mi][ni], 0, 0, 0);
        }
        __syncthreads();
    }
    const int rbase = (lane >> 4) * 4;
    #pragma unroll
    for (int mi = 0; mi < 4; ++mi) {
        #pragma unroll
        for (int ni = 0; ni < 4; ++ni) {
            int col = n0 + wc * 64 + ni * 16 + ml;
            float bv = HAS_BIAS ? bias[col] : 0.f;
            #pragma unroll
            for (int r = 0; r < 4; ++r) {
                int row = m0 + wr * 64 + mi * 16 + rbase + r;
                float v = acc[mi][ni][r] + bv;
                if constexpr (BF16_OUT)
                    ((bf16*)Cout)[(size_t)row * N + col] = (bf16)v;
                else
                    ((float*)Cout)[(size_t)row * N + col] = v;
            }
        }
    }
}

// ---------------------------------------------------------------------------
// [16 rows x 1024] @ [1024 x 48-col LDS slice] -> acc[3] per thread.
// CACHED inline-asm loads, all 32 quads in flight, staged vmcnt(16)/vmcnt(0).
// NOTE: counted waits stay correct if up to a few OLDER loads (e.g. role2's
// gx2 u64 loads) are still outstanding at entry — in-order retirement means
// vmcnt(16) leaves only the NEWEST 16 (hq[16..31]) pending.
__device__ __forceinline__ void mm_step(const char* sW, const bf16* hsrc,
                                        int myrow, int kb, int ml, f32x4 acc[3]) {
    const char* rowp = (const char*)(hsrc + (size_t)myrow * 1024) + kb * 2;
    uint4 hq[32];
    #pragma unroll
    for (int ks = 0; ks < 32; ++ks)
        asm volatile("global_load_dwordx4 %0, %1, off"
                     : "=v"(hq[ks]) : "v"(rowp + ks * 64) : "memory");
    asm volatile("s_waitcnt vmcnt(16)" ::: "memory");
    __builtin_amdgcn_sched_barrier(0);
    #pragma unroll
    for (int ks = 0; ks < 16; ++ks) {
        bf16x8 af = __builtin_bit_cast(bf16x8, hq[ks]);
        #pragma unroll
        for (int g = 0; g < 3; ++g) {
            int brow = g * 16 + ml;
            int addr = brow * 2048 + (ks * 32 + kb) * 2;
            addr ^= (brow & 7) << 4;
            bf16x8 bw = *(const bf16x8*)(sW + addr);
            acc[g] = __builtin_amdgcn_mfma_f32_16x16x32_bf16(af, bw, acc[g], 0, 0, 0);
        }
    }
    asm volatile("s_waitcnt vmcnt(0)" ::: "memory");
    __builtin_amdgcn_sched_barrier(0);
    #pragma unroll
    for (int ks = 16; ks < 32; ++ks) {
        bf16x8 af = __builtin_bit_cast(bf16x8, hq[ks]);
        #pragma unroll
        for (int g = 0; g < 3; ++g) {
            int brow = g * 16 + ml;
            int addr = brow * 2048 + (ks * 32 + kb) * 2;
            addr ^= (brow & 7) << 4;
            bf16x8 bw = *(const bf16x8*)(sW + addr);
            acc[g] = __builtin_amdgcn_mfma_f32_16x16x32_bf16(af, bw, acc[g], 0, 0, 0);
        }
    }
}

__device__ __forceinline__ void store_pair_sc(bf16* base, size_t idx,
                                              unsigned short v, int ml) {
    unsigned nb = (unsigned)__shfl_xor((int)(unsigned)v, 1, 64);
    if ((ml & 1) == 0) {
        unsigned pk = (unsigned)v | (nb << 16);
        __hip_atomic_store((unsigned*)(base + idx), pk,
                           __ATOMIC_RELAXED, __HIP_MEMORY_SCOPE_AGENT);
    }
}

// coalesced 64-lane poll of one u16 flag group (2 cache lines, 0.21us grain)
__device__ __forceinline__ void poll1(const u16* a, unsigned ta, int lane) {
    while (true) {
        unsigned fa = (unsigned)__hip_atomic_load(a + lane, __ATOMIC_RELAXED,
                                                  __HIP_MEMORY_SCOPE_AGENT);
        if (__all((int)(fa >= ta))) break;
        __builtin_amdgcn_s_sleep(8);
    }
    asm volatile("" ::: "memory");
}

__device__ __forceinline__ void publish1(u16* s1, unsigned val, int lane) {
    asm volatile("s_waitcnt vmcnt(0)" ::: "memory");
    if (lane == 0)
        __hip_atomic_store(s1, (u16)val, __ATOMIC_RELAXED, __HIP_MEMORY_SCOPE_AGENT);
}
__device__ __forceinline__ void publish2(u16* s1, u16* s2, unsigned val, int lane) {
    asm volatile("s_waitcnt vmcnt(0)" ::: "memory");
    if (lane == 0) {
        __hip_atomic_store(s1, (u16)val, __ATOMIC_RELAXED, __HIP_MEMORY_SCOPE_AGENT);
        __hip_atomic_store(s2, (u16)val, __ATOMIC_RELAXED, __HIP_MEMORY_SCOPE_AGENT);
    }
}

// ---------------------------------------------------------------------------
// Fused 2-layer GRU pipeline (r15 structure, contention-trimmed), 192 blocks:
//  role 0 (blk 0..63):   layer-1 scan -> h1[t]
//  role 1 (blk 64..127): gx2[t] = h1[t] @ W2f -> 16-slot transposed ring
//  role 2 (blk 128..191):layer-2 scan -> hs2[t]
// vs r15: u16 flags (poll = 2 lines not 4), s_sleep(8), split polls so gx2
// loads / back-pressure waits overlap other latency. Per-consumer flag copies.
__global__ __launch_bounds__(256, 1) void gru_fused(
    const bf16* __restrict__ WH1T, const bf16* __restrict__ W2fT,
    const bf16* __restrict__ WH2T, const bf16* __restrict__ gx1,
    const float* __restrict__ pad, const float* __restrict__ b2,
    bf16* __restrict__ h1,       // [512][64][1024]
    bf16* __restrict__ gx2ring,  // 16 x [3][1024][64]  (transposed)
    bf16* __restrict__ hs2,      // [512][64][1024]
    u16* __restrict__ f1s, u16* __restrict__ f1c,
    u16* __restrict__ f2,
    u16* __restrict__ f3s, u16* __restrict__ f3c) {
    extern __shared__ __align__(16) char sW[];   // 48 x 2048 B, swizzled

    const int tid = threadIdx.x, lane = tid & 63, wv = tid >> 6;
    const int role = blockIdx.x >> 6, jg = blockIdx.x & 63;
    const int j0 = jg * 16;
    const int ml = lane & 15, kb = (lane >> 4) * 8;
    const int rbase = (lane >> 4) * 4;
    const int myrow = wv * 16 + ml;
    const int bbase = wv * 16 + rbase;
    const int jml = j0 + ml;

    // ---- load this role's 48x1024 weight slice into LDS (rows gate*16+j)
    const bf16* Wsrc = (role == 0) ? WH1T : (role == 1) ? W2fT : WH2T;
    #pragma unroll 1
    for (int i = 0; i < 24; ++i) {
        int c = tid + 256 * i;
        int rr = c >> 7;
        int off = (c & 127) * 16;
        int gate = rr >> 4, j = rr & 15;
        const bf16* src = Wsrc + (size_t)(gate * 1024 + j0 + j) * 1024 + off / 2;
        *(uint4*)(sW + rr * 2048 + (off ^ ((rr & 7) << 4))) = *(const uint4*)src;
    }
    __syncthreads();   // sW read-only afterwards; waves free-run

    if (role == 0) {
        // ================= layer-1 scan =================
        u16* fown = f1s + wv * 64;
        float hreg[4] = {0.f, 0.f, 0.f, 0.f};
        float gxv[12]; float4 pv;
        #pragma unroll
        for (int r = 0; r < 4; ++r) {
            size_t b = (size_t)(bbase + r);
            gxv[r * 3 + 0] = (float)gx1[b * 3072 + jml];
            gxv[r * 3 + 1] = (float)gx1[b * 3072 + 1024 + jml];
            gxv[r * 3 + 2] = (float)gx1[b * 3072 + 2048 + jml];
        }
        pv = *(const float4*)(pad + bbase);

        for (int t = 0; t < 512; ++t) {
            f32x4 acc[3] = {};
            if (t > 0) {
                poll1(fown, (unsigned)t, lane);
                mm_step(sW, h1 + (size_t)(t - 1) * 65536, myrow, kb, ml, acc);
            }
            unsigned short hpk[4];
            #pragma unroll
            for (int r = 0; r < 4; ++r) {
                float rr = 1.f / (1.f + __expf(-(gxv[r * 3 + 0] + acc[0][r])));
                float zz = 1.f / (1.f + __expf(-(gxv[r * 3 + 1] + acc[1][r])));
                float nn = tanhf(gxv[r * 3 + 2] + rr * acc[2][r]);
                float hold = hreg[r];
                float hn = (1.f - zz) * nn + zz * hold;
                float p = (r == 0) ? pv.x : (r == 1) ? pv.y : (r == 2) ? pv.z : pv.w;
                hn = p * hold + (1.f - p) * hn;
                hreg[r] = hn;
                hpk[r] = __builtin_bit_cast(unsigned short, (bf16)hn);
            }
            bf16* hst = h1 + (size_t)t * 65536;
            #pragma unroll
            for (int r = 0; r < 4; ++r)
                store_pair_sc(hst, (size_t)(bbase + r) * 1024 + jml, hpk[r], ml);
            publish2(fown + jg, f1c + wv * 64 + jg, (unsigned)(t + 1), lane);
            {   // prefetch gx1 + pad for t+1 (cached; drains during next poll)
                int tn = (t < 511) ? t + 1 : 511;
                const bf16* gxt = gx1 + (size_t)tn * 64 * 3072;
                #pragma unroll
                for (int r = 0; r < 4; ++r) {
                    size_t b = (size_t)(bbase + r);
                    gxv[r * 3 + 0] = (float)gxt[b * 3072 + jml];
                    gxv[r * 3 + 1] = (float)gxt[b * 3072 + 1024 + jml];
                    gxv[r * 3 + 2] = (float)gxt[b * 3072 + 2048 + jml];
                }
                pv = *(const float4*)(pad + tn * 64 + bbase);
            }
        }
    } else if (role == 1) {
        // ================= gx2 producer =================
        u16* fsrc = f1c + wv * 64;
        u16* fbp  = f3c + wv * 64;
        for (int t = 0; t < 512; ++t) {
            poll1(fsrc, (unsigned)(t + 1), lane);     // h1[t] ready
            f32x4 acc[3] = {};
            mm_step(sW, h1 + (size_t)t * 65536, myrow, kb, ml, acc);
            if (t >= 16)                              // back-pressure only gates STORES
                poll1(fbp, (unsigned)(t - 15), lane);
            // transposed store: [g][col jml][rows bbase..+3] -> one 8B store per g
            bf16* dst = gx2ring + (size_t)(t & 15) * 196608;
            #pragma unroll
            for (int g = 0; g < 3; ++g) {
                unsigned short w0 = __builtin_bit_cast(unsigned short, (bf16)acc[g][0]);
                unsigned short w1 = __builtin_bit_cast(unsigned short, (bf16)acc[g][1]);
                unsigned short w2 = __builtin_bit_cast(unsigned short, (bf16)acc[g][2]);
                unsigned short w3 = __builtin_bit_cast(unsigned short, (bf16)acc[g][3]);
                u64 pk = (u64)w0 | ((u64)w1 << 16) | ((u64)w2 << 32) | ((u64)w3 << 48);
                __hip_atomic_store((u64*)(dst + ((size_t)(g * 1024 + jml)) * 64 + bbase),
                                   pk, __ATOMIC_RELAXED, __HIP_MEMORY_SCOPE_AGENT);
            }
            publish1(f2 + wv * 64 + jg, (unsigned)(t + 1), lane);
        }
    } else {
        // ================= layer-2 scan =================
        u16* fown = f3s + wv * 64;
        u16* fgx  = f2 + wv * 64;
        float b2v[3] = {b2[jml], b2[1024 + jml], b2[2048 + jml]};
        float hreg[4] = {0.f, 0.f, 0.f, 0.f};
        float4 pv = *(const float4*)(pad + bbase);

        for (int t = 0; t < 512; ++t) {
            poll1(fgx, (unsigned)(t + 1), lane);      // gx2 slot t ready
            // issue gx2 loads now; they drain during the fown poll below
            const bf16* gsl = gx2ring + (size_t)(t & 15) * 196608;
            u64 gq[3];
            #pragma unroll
            for (int g = 0; g < 3; ++g)
                gq[g] = __hip_atomic_load(
                    (const u64*)(gsl + ((size_t)(g * 1024 + jml)) * 64 + bbase),
                    __ATOMIC_RELAXED, __HIP_MEMORY_SCOPE_AGENT);
            f32x4 acc[3] = {};
            if (t > 0) {
                poll1(fown, (unsigned)t, lane);       // hs2[t-1] ready
                mm_step(sW, hs2 + (size_t)(t - 1) * 65536, myrow, kb, ml, acc);
            }
            unsigned short hpk[4];
            #pragma unroll
            for (int r = 0; r < 4; ++r) {
                float gr = (float)__builtin_bit_cast(bf16,
                    (unsigned short)(gq[0] >> (r * 16))) + b2v[0];
                float gz = (float)__builtin_bit_cast(bf16,
                    (unsigned short)(gq[1] >> (r * 16))) + b2v[1];
                float gn = (float)__builtin_bit_cast(bf16,
                    (unsigned short)(gq[2] >> (r * 16))) + b2v[2];
                float rr = 1.f / (1.f + __expf(-(gr + acc[0][r])));
                float zz = 1.f / (1.f + __expf(-(gz + acc[1][r])));
                float nn = tanhf(gn + rr * acc[2][r]);
                float hold = hreg[r];
                float hn = (1.f - zz) * nn + zz * hold;
                float p = (r == 0) ? pv.x : (r == 1) ? pv.y : (r == 2) ? pv.z : pv.w;
                hn = p * hold + (1.f - p) * hn;
                hreg[r] = hn;
                hpk[r] = __builtin_bit_cast(unsigned short, (bf16)hn);
            }
            bf16* hst = hs2 + (size_t)t * 65536;
            #pragma unroll
            for (int r = 0; r < 4; ++r)
                store_pair_sc(hst, (size_t)(bbase + r) * 1024 + jml, hpk[r], ml);
            publish2(fown + jg, f3c + wv * 64 + jg, (unsigned)(t + 1), lane);
            int tn = (t < 511) ? t + 1 : 511;
            pv = *(const float4*)(pad + tn * 64 + bbase);
        }
    }
}

// ---------------------------------------------------------------------------
extern "C" void kernel_launch(void* const* d_in, const int* in_sizes, int n_in,
                              void* d_out, int out_size, void* d_ws, size_t ws_size,
                              hipStream_t stream) {
    const float* x    = (const float*)d_in[0];
    const float* pad  = (const float*)d_in[1];
    const float* Wih1 = (const float*)d_in[2];
    const float* Whh1 = (const float*)d_in[3];
    const float* b1   = (const float*)d_in[4];
    const float* Who1 = (const float*)d_in[5];
    const float* Wih2 = (const float*)d_in[6];
    const float* Whh2 = (const float*)d_in[7];
    const float* b2   = (const float*)d_in[8];
    const float* Who2 = (const float*)d_in[9];
    float* out_f = (float*)d_out;

    char* p = (char*)d_ws;
    bf16* xb      = (bf16*)p; p += (size_t)32768 * 1024 * 2;  //  64MB
    bf16* gxb     = (bf16*)p; p += (size_t)32768 * 3072 * 2;  // 192MB (gx1)
    bf16* h1      = (bf16*)p; p += (size_t)32768 * 1024 * 2;  //  64MB
    bf16* hs2     = (bf16*)p; p += (size_t)32768 * 1024 * 2;  //  64MB
    bf16* gx2ring = (bf16*)p; p += (size_t)16 * 196608 * 2;   //   6MB
    bf16* WT1     = (bf16*)p; p += (size_t)3072 * 1024 * 2;   //   6MB
    bf16* who1b   = (bf16*)p; p += (size_t)1024 * 1024 * 2;   //   2MB
    bf16* W2fT    = (bf16*)p; p += (size_t)3072 * 1024 * 2;   //   6MB
    bf16* WH1     = (bf16*)p; p += (size_t)3072 * 1024 * 2;   //   6MB
    bf16* WH2     = (bf16*)p; p += (size_t)3072 * 1024 * 2;   //   6MB
    u16* flags = (u16*)p; p += 8192;
    u16* f1s = flags,        * f1c = flags + 256;
    u16* f2  = flags + 512;
    u16* f3s = flags + 768,  * f3c = flags + 1024;

    hipFuncSetAttribute((const void*)gru_fused,
                        hipFuncAttributeMaxDynamicSharedMemorySize, 131072);

    // 1. x -> bf16
    cast_f32_bf16<<<16384, 256, 0, stream>>>(x, xb);
    // 2. gx1 = x @ Wih1 + b1
    transpose_cast<<<dim3(96, 32), 256, 0, stream>>>(Wih1, WT1, 1024, 3072);
    gemm128<true, true><<<dim3(24, 256), 256, 0, stream>>>(
        xb, WT1, b1, gxb, 32768, 3072, 1024);
    // 3. W2fT = (Who1 @ Wih2)^T  (verified recipe)
    transpose_cast<<<dim3(96, 32), 256, 0, stream>>>(Wih2, WT1, 1024, 3072);
    cast_f32_bf16<<<512, 256, 0, stream>>>(Who1, who1b);
    gemm128<true, false><<<dim3(8, 24), 256, 0, stream>>>(
        WT1, who1b, nullptr, W2fT, 3072, 1024, 1024);
    // 4. recurrent weights; Who2T into WT1 (stream-ordered reuse)
    transpose_cast<<<dim3(96, 32), 256, 0, stream>>>(Whh1, WH1, 1024, 3072);
    transpose_cast<<<dim3(96, 32), 256, 0, stream>>>(Whh2, WH2, 1024, 3072);
    transpose_cast<<<dim3(32, 32), 256, 0, stream>>>(Who2, WT1, 1024, 1024);
    hipMemsetAsync(flags, 0, 8192, stream);
    // 5. fused pipelined 2-layer scan
    gru_fused<<<192, 256, 98304, stream>>>(WH1, W2fT, WH2, gxb, pad, b2,
                                           h1, gx2ring, hs2,
                                           f1s, f1c, f2, f3s, f3c);
    // 6. out = hs2 @ Who2 (f32)
    gemm128<false, false><<<dim3(8, 256), 256, 0, stream>>>(
        hs2, WT1, nullptr, out_f, 32768, 1024, 1024);
}